// Round 1
// baseline (165.914 us; speedup 1.0000x reference)
//
#include <hip/hip_runtime.h>
#include <stdint.h>
#include <stddef.h>

// NMI loss: x,y (64,1,512,512) f32 -> downsample ::2 -> +threefry noise*1e-4
// -> 24-bin joint hist per batch -> NMI -> -clip(mean,-1,1).
//
// Noise reproduces JAX's threefry2x32-20 stream under the modern default
// jax_threefry_partitionable=True:
//   key(42) = (0,42); split foldlike: nk_i = tf((0,42), (0,i)) both words;
//   bits(n) = out0 ^ out1 of tf(nk, (0, n)); u = bits>>9 |0x3f800000 -1
//   -> u*2 + nextafter(-1,0), max(lo,.); normal = sqrt(2)*erfinv(u) (XLA poly).

#define NB 24
#define NBINS 576          // 24*24
#define NBATCH 64
#define SPB 65536          // samples per batch = 256*256
#define HIST_BPB 16        // hist blocks per batch
#define HIST_THREADS 256

__host__ __device__ __forceinline__ uint32_t rotl32_(uint32_t x, uint32_t r) {
  return (x << r) | (x >> (32u - r));
}

// Threefry-2x32, 20 rounds (JAX semantics). x0,x1 carry counts in, bits out.
__host__ __device__ inline void threefry2x32_(uint32_t k0, uint32_t k1,
                                              uint32_t& x0, uint32_t& x1) {
  const uint32_t k2 = k0 ^ k1 ^ 0x1BD11BDAu;
  x0 += k0; x1 += k1;
#define TFR(r) { x0 += x1; x1 = rotl32_(x1, (r)); x1 ^= x0; }
  TFR(13u) TFR(15u) TFR(26u) TFR(6u)
  x0 += k1; x1 += k2 + 1u;
  TFR(17u) TFR(29u) TFR(16u) TFR(24u)
  x0 += k2; x1 += k0 + 2u;
  TFR(13u) TFR(15u) TFR(26u) TFR(6u)
  x0 += k0; x1 += k1 + 3u;
  TFR(17u) TFR(29u) TFR(16u) TFR(24u)
  x0 += k1; x1 += k2 + 4u;
  TFR(13u) TFR(15u) TFR(26u) TFR(6u)
  x0 += k2; x1 += k0 + 5u;
#undef TFR
}

// XLA ErfInv f32 (Giles polynomial) — matches jax.lax.erf_inv lowering.
__device__ __forceinline__ float erfinv32_(float x) {
  float w = -log1pf(-x * x);
  float p;
  if (w < 5.0f) {
    w -= 2.5f;
    p =  2.81022636e-08f;
    p = fmaf(p, w,  3.43273939e-07f);
    p = fmaf(p, w, -3.5233877e-06f);
    p = fmaf(p, w, -4.39150654e-06f);
    p = fmaf(p, w,  0.00021858087f);
    p = fmaf(p, w, -0.00125372503f);
    p = fmaf(p, w, -0.00417768164f);
    p = fmaf(p, w,  0.246640727f);
    p = fmaf(p, w,  1.50140941f);
  } else {
    w = sqrtf(w) - 3.0f;
    p = -0.000200214257f;
    p = fmaf(p, w,  0.000100950558f);
    p = fmaf(p, w,  0.00134934322f);
    p = fmaf(p, w, -0.00367342844f);
    p = fmaf(p, w,  0.00573950773f);
    p = fmaf(p, w, -0.0076224613f);
    p = fmaf(p, w,  0.00943887047f);
    p = fmaf(p, w,  1.00167406f);
    p = fmaf(p, w,  2.83297682f);
  }
  return p * x;
}

__device__ __forceinline__ float tf_normal_(uint32_t ka, uint32_t kb, uint32_t n) {
  uint32_t x0 = 0u, x1 = n;          // counter hi=0 (n < 2^32), lo=n
  threefry2x32_(ka, kb, x0, x1);
  const uint32_t bits = x0 ^ x1;     // 32-bit partitionable output
  float f = __uint_as_float((bits >> 9) | 0x3F800000u) - 1.0f;  // [0,1)
  const float lo = -0.99999994f;     // nextafter(-1,0) in f32
  float u = f * 2.0f + lo;           // f*(hi-lo)+lo, hi-lo rounds to 2.0f
  u = fmaxf(lo, u);
  return 1.41421356f * erfinv32_(u); // sqrt(2) in f32
}

__global__ __launch_bounds__(HIST_THREADS) void nmi_hist_kernel(
    const float* __restrict__ x, const float* __restrict__ y,
    uint32_t* __restrict__ ghist,
    uint32_t nk1a, uint32_t nk1b, uint32_t nk2a, uint32_t nk2b) {
  __shared__ uint32_t h[NBINS];
  for (int t = threadIdx.x; t < NBINS; t += HIST_THREADS) h[t] = 0u;
  __syncthreads();

  const int b    = blockIdx.x / HIST_BPB;
  const int blk  = blockIdx.x % HIST_BPB;
  const int per  = SPB / HIST_BPB;     // 4096 samples per block
  const int base = blk * per;
  const float* __restrict__ xb = x + (size_t)b * 262144;  // 512*512
  const float* __restrict__ yb = y + (size_t)b * 262144;
  const uint32_t nbase = (uint32_t)b * (uint32_t)SPB;

  for (int i = threadIdx.x; i < per; i += HIST_THREADS) {
    const int s  = base + i;          // sample index in [0, 65536)
    const int hh = s >> 8;            // row in downsampled 256x256
    const int ww = s & 255;           // col
    const int src = (hh << 10) + (ww << 1);   // (2h)*512 + 2w
    float xv = xb[src];
    float yv = yb[src];
    const uint32_t n = nbase + (uint32_t)s;   // flat index into noise array
    xv = xv + tf_normal_(nk1a, nk1b, n) * 1e-4f;
    yv = yv + tf_normal_(nk2a, nk2b, n) * 1e-4f;
    float vx = (xv + 1.0f) * 0.5f;
    float vy = (yv + 1.0f) * 0.5f;
    vx = fminf(fmaxf(vx, 0.001f), 0.999f);
    vy = fminf(fmaxf(vy, 0.001f), 0.999f);
    int bx = (int)floorf(vx * 24.0f);
    int by = (int)floorf(vy * 24.0f);
    bx = bx < 0 ? 0 : (bx > 23 ? 23 : bx);
    by = by < 0 ? 0 : (by > 23 ? 23 : by);
    atomicAdd(&h[bx * NB + by], 1u);
  }
  __syncthreads();

  uint32_t* gh = ghist + b * NBINS;
  for (int t = threadIdx.x; t < NBINS; t += HIST_THREADS) {
    const uint32_t c = h[t];
    if (c) atomicAdd(&gh[t], c);
  }
}

__global__ __launch_bounds__(256) void nmi_reduce_kernel(
    const uint32_t* __restrict__ ghist, float* __restrict__ nmi_out) {
  const int b = blockIdx.x;
  __shared__ float joint[NBINS];
  __shared__ float xh[NB];
  __shared__ float yh[NB];
  __shared__ float red_mi[4];
  __shared__ float red_h[4];

  const uint32_t* gh = ghist + b * NBINS;
  for (int t = threadIdx.x; t < NBINS; t += 256)
    joint[t] = (float)gh[t] * (1.0f / 65536.0f);   // total==65536 exactly
  __syncthreads();

  if (threadIdx.x < NB) {
    const int i = threadIdx.x;
    float sx = 0.f, sy = 0.f;
    for (int j = 0; j < NB; ++j) {
      sx += joint[i * NB + j];   // x_hist[i]
      sy += joint[j * NB + i];   // y_hist[i]
    }
    xh[i] = sx; yh[i] = sy;
  }
  __syncthreads();

  float mi_part = 0.f;
  for (int t = threadIdx.x; t < NBINS; t += 256) {
    const int i = t / NB, j = t % NB;
    const float je = joint[t] + 1e-5f;
    const float pe = (xh[i] + 1e-5f) * (yh[j] + 1e-5f);
    mi_part += je * (logf(je) - logf(pe));
  }
  float h_part = 0.f;
  if (threadIdx.x < NB) {
    const float e = xh[threadIdx.x] + 1e-5f;
    h_part = -(e * logf(e));                        // hx term
  } else if (threadIdx.x >= 64 && threadIdx.x < 64 + NB) {
    const float e = yh[threadIdx.x - 64] + 1e-5f;
    h_part = -(e * logf(e));                        // hy term
  }

  for (int o = 32; o > 0; o >>= 1) {
    mi_part += __shfl_down(mi_part, o);
    h_part  += __shfl_down(h_part, o);
  }
  const int wid  = threadIdx.x >> 6;
  const int lane = threadIdx.x & 63;
  if (lane == 0) { red_mi[wid] = mi_part; red_h[wid] = h_part; }
  __syncthreads();
  if (threadIdx.x == 0) {
    const float mi = red_mi[0] + red_mi[1] + red_mi[2] + red_mi[3];
    const float se = red_h[0] + red_h[1] + red_h[2] + red_h[3];  // hx + hy
    float nmi = (se < 1e-10f) ? 0.0f : (2.0f * mi / se);
    nmi = fminf(fmaxf(nmi, -1.0f), 1.0f);
    nmi_out[b] = nmi;
  }
}

__global__ void nmi_final_kernel(const float* __restrict__ nmi,
                                 float* __restrict__ out) {
  float v = nmi[threadIdx.x];                      // 64 threads, one wave
  for (int o = 32; o > 0; o >>= 1) v += __shfl_down(v, o);
  if (threadIdx.x == 0) {
    float m = v * (1.0f / 64.0f);                  // mean (exact /2^6)
    m = fminf(fmaxf(m, -1.0f), 1.0f);
    out[0] = -m;
  }
}

extern "C" void kernel_launch(void* const* d_in, const int* in_sizes, int n_in,
                              void* d_out, int out_size, void* d_ws, size_t ws_size,
                              hipStream_t stream) {
  const float* x = (const float*)d_in[0];
  const float* y = (const float*)d_in[1];
  float* out = (float*)d_out;

  uint32_t* ghist = (uint32_t*)d_ws;
  float* nmi = (float*)((char*)d_ws + (size_t)NBATCH * NBINS * sizeof(uint32_t));

  // Host-side key derivation (pure CPU arithmetic, graph-capture safe):
  // jax.random.split(jax.random.key(42)) under threefry_partitionable:
  //   nk_i = threefry2x32((0,42), count=(hi=0, lo=i)), both output words.
  uint32_t nk1a = 0u, nk1b = 0u; threefry2x32_(0u, 42u, nk1a, nk1b);
  uint32_t nk2a = 0u, nk2b = 1u; threefry2x32_(0u, 42u, nk2a, nk2b);

  hipMemsetAsync(ghist, 0, (size_t)NBATCH * NBINS * sizeof(uint32_t), stream);
  nmi_hist_kernel<<<NBATCH * HIST_BPB, HIST_THREADS, 0, stream>>>(
      x, y, ghist, nk1a, nk1b, nk2a, nk2b);
  nmi_reduce_kernel<<<NBATCH, 256, 0, stream>>>(ghist, nmi);
  nmi_final_kernel<<<1, 64, 0, stream>>>(nmi, out);
}

// Round 2
// 138.163 us; speedup vs baseline: 1.2009x; 1.2009x over previous
//
#include <hip/hip_runtime.h>
#include <stdint.h>
#include <stddef.h>

// NMI loss: x,y (64,1,512,512) f32 -> downsample ::2 -> +threefry noise*1e-4
// -> 24-bin joint hist per batch -> NMI -> -clip(mean,-1,1).
//
// Noise reproduces JAX's threefry2x32-20 stream (jax_threefry_partitionable
// default). OPTIMIZATION (R2): noise |delta_t| <= 6.54e-3 bin-units, so any
// sample with frac(t) in [MARGIN, 1-MARGIN] has a provably noise-invariant
// bin -> fast path without threefry. Boundary samples (~3.2%) are compacted
// into an LDS queue and processed densely in phase 2 with the exact
// (verified absmax==0) noisy path.

#define NB 24
#define NBINS 576          // 24*24
#define NBATCH 64
#define SPB 65536          // samples per batch = 256*256
#define HIST_BPB 16        // hist blocks per batch
#define HIST_THREADS 512
#define PER_BLOCK 4096     // SPB / HIST_BPB
#define QCAP 1024          // LDS queue capacity (expected load ~131)
#define MARGIN 0.008f      // > 6.54e-3 worst-case noise swing in bin units

__host__ __device__ __forceinline__ uint32_t rotl32_(uint32_t x, uint32_t r) {
  return (x << r) | (x >> (32u - r));
}

// Threefry-2x32, 20 rounds (JAX semantics). x0,x1 carry counts in, bits out.
__host__ __device__ inline void threefry2x32_(uint32_t k0, uint32_t k1,
                                              uint32_t& x0, uint32_t& x1) {
  const uint32_t k2 = k0 ^ k1 ^ 0x1BD11BDAu;
  x0 += k0; x1 += k1;
#define TFR(r) { x0 += x1; x1 = rotl32_(x1, (r)); x1 ^= x0; }
  TFR(13u) TFR(15u) TFR(26u) TFR(6u)
  x0 += k1; x1 += k2 + 1u;
  TFR(17u) TFR(29u) TFR(16u) TFR(24u)
  x0 += k2; x1 += k0 + 2u;
  TFR(13u) TFR(15u) TFR(26u) TFR(6u)
  x0 += k0; x1 += k1 + 3u;
  TFR(17u) TFR(29u) TFR(16u) TFR(24u)
  x0 += k1; x1 += k2 + 4u;
  TFR(13u) TFR(15u) TFR(26u) TFR(6u)
  x0 += k2; x1 += k0 + 5u;
#undef TFR
}

// XLA ErfInv f32 (Giles polynomial) — matches jax.lax.erf_inv lowering.
__device__ __forceinline__ float erfinv32_(float x) {
  float w = -log1pf(-x * x);
  float p;
  if (w < 5.0f) {
    w -= 2.5f;
    p =  2.81022636e-08f;
    p = fmaf(p, w,  3.43273939e-07f);
    p = fmaf(p, w, -3.5233877e-06f);
    p = fmaf(p, w, -4.39150654e-06f);
    p = fmaf(p, w,  0.00021858087f);
    p = fmaf(p, w, -0.00125372503f);
    p = fmaf(p, w, -0.00417768164f);
    p = fmaf(p, w,  0.246640727f);
    p = fmaf(p, w,  1.50140941f);
  } else {
    w = sqrtf(w) - 3.0f;
    p = -0.000200214257f;
    p = fmaf(p, w,  0.000100950558f);
    p = fmaf(p, w,  0.00134934322f);
    p = fmaf(p, w, -0.00367342844f);
    p = fmaf(p, w,  0.00573950773f);
    p = fmaf(p, w, -0.0076224613f);
    p = fmaf(p, w,  0.00943887047f);
    p = fmaf(p, w,  1.00167406f);
    p = fmaf(p, w,  2.83297682f);
  }
  return p * x;
}

__device__ __forceinline__ float tf_normal_(uint32_t ka, uint32_t kb, uint32_t n) {
  uint32_t x0 = 0u, x1 = n;          // counter hi=0 (n < 2^32), lo=n
  threefry2x32_(ka, kb, x0, x1);
  const uint32_t bits = x0 ^ x1;     // 32-bit partitionable output
  float f = __uint_as_float((bits >> 9) | 0x3F800000u) - 1.0f;  // [0,1)
  const float lo = -0.99999994f;     // nextafter(-1,0) in f32
  float u = f * 2.0f + lo;           // f*(hi-lo)+lo, hi-lo rounds to 2.0f
  u = fmaxf(lo, u);
  return 1.41421356f * erfinv32_(u); // sqrt(2) in f32
}

__global__ __launch_bounds__(HIST_THREADS) void nmi_hist_kernel(
    const float* __restrict__ x, const float* __restrict__ y,
    uint32_t* __restrict__ ghist,
    uint32_t nk1a, uint32_t nk1b, uint32_t nk2a, uint32_t nk2b) {
  __shared__ uint32_t h[NBINS];
  __shared__ uint16_t q[QCAP];
  __shared__ uint32_t qn;
  for (int t = threadIdx.x; t < NBINS; t += HIST_THREADS) h[t] = 0u;
  if (threadIdx.x == 0) qn = 0u;
  __syncthreads();

  const int b    = blockIdx.x / HIST_BPB;
  const int blk  = blockIdx.x % HIST_BPB;
  const int base = blk * PER_BLOCK;
  const float* __restrict__ xb = x + (size_t)b * 262144;  // 512*512
  const float* __restrict__ yb = y + (size_t)b * 262144;
  const uint32_t nbase = (uint32_t)b * (uint32_t)SPB;

  // Phase 1: fast path. Bin w/o noise; provably noise-invariant unless the
  // fractional bin coordinate is within MARGIN of a boundary.
  #pragma unroll
  for (int k = 0; k < PER_BLOCK / HIST_THREADS; ++k) {
    const int i = k * HIST_THREADS + (int)threadIdx.x;
    const int s = base + i;                    // sample index in [0, 65536)
    const int src = ((s >> 8) << 10) + ((s & 255) << 1);  // (2h)*512 + 2w
    const float xv = xb[src];
    const float yv = yb[src];
    const float tx = fminf(fmaxf((xv + 1.0f) * 0.5f, 0.001f), 0.999f) * 24.0f;
    const float ty = fminf(fmaxf((yv + 1.0f) * 0.5f, 0.001f), 0.999f) * 24.0f;
    const float fx = floorf(tx), fy = floorf(ty);
    const float rx = tx - fx,   ry = ty - fy;
    // t in [0.024, 23.976] -> (int)fx,(int)fy already in [0,23]
    const bool safe = (rx >= MARGIN) & (rx <= 1.0f - MARGIN) &
                      (ry >= MARGIN) & (ry <= 1.0f - MARGIN);
    if (safe) {
      atomicAdd(&h[(int)fx * NB + (int)fy], 1u);
    } else {
      const uint32_t qi = atomicAdd(&qn, 1u);
      if (qi < QCAP) {
        q[qi] = (uint16_t)i;
      } else {
        // overflow fallback (statistically unreachable): exact inline
        const uint32_t n = nbase + (uint32_t)s;
        const float xn = xv + tf_normal_(nk1a, nk1b, n) * 1e-4f;
        const float yn = yv + tf_normal_(nk2a, nk2b, n) * 1e-4f;
        const float vx = fminf(fmaxf((xn + 1.0f) * 0.5f, 0.001f), 0.999f);
        const float vy = fminf(fmaxf((yn + 1.0f) * 0.5f, 0.001f), 0.999f);
        int bx = (int)floorf(vx * 24.0f);
        int by = (int)floorf(vy * 24.0f);
        bx = bx < 0 ? 0 : (bx > 23 ? 23 : bx);
        by = by < 0 ? 0 : (by > 23 ? 23 : by);
        atomicAdd(&h[bx * NB + by], 1u);
      }
    }
  }
  __syncthreads();

  // Phase 2: dense exact path for boundary samples (all lanes active).
  const uint32_t nq = qn < QCAP ? qn : (uint32_t)QCAP;
  for (uint32_t j = threadIdx.x; j < nq; j += HIST_THREADS) {
    const int i = (int)q[j];
    const int s = base + i;
    const int src = ((s >> 8) << 10) + ((s & 255) << 1);
    const uint32_t n = nbase + (uint32_t)s;
    const float xn = xb[src] + tf_normal_(nk1a, nk1b, n) * 1e-4f;
    const float yn = yb[src] + tf_normal_(nk2a, nk2b, n) * 1e-4f;
    const float vx = fminf(fmaxf((xn + 1.0f) * 0.5f, 0.001f), 0.999f);
    const float vy = fminf(fmaxf((yn + 1.0f) * 0.5f, 0.001f), 0.999f);
    int bx = (int)floorf(vx * 24.0f);
    int by = (int)floorf(vy * 24.0f);
    bx = bx < 0 ? 0 : (bx > 23 ? 23 : bx);
    by = by < 0 ? 0 : (by > 23 ? 23 : by);
    atomicAdd(&h[bx * NB + by], 1u);
  }
  __syncthreads();

  uint32_t* gh = ghist + b * NBINS;
  for (int t = threadIdx.x; t < NBINS; t += HIST_THREADS) {
    const uint32_t c = h[t];
    if (c) atomicAdd(&gh[t], c);
  }
}

// Fused per-batch NMI + grid-wide mean (last-block ticket, agent-scope
// atomics for cross-XCD coherence).
__global__ __launch_bounds__(256) void nmi_reduce_kernel(
    const uint32_t* __restrict__ ghist, float* __restrict__ nmi_arr,
    uint32_t* __restrict__ ctr, float* __restrict__ out) {
  const int b = blockIdx.x;
  __shared__ float joint[NBINS];
  __shared__ float xh[NB];
  __shared__ float yh[NB];
  __shared__ float red_mi[4];
  __shared__ float red_h[4];
  __shared__ int islast;

  const uint32_t* gh = ghist + b * NBINS;
  for (int t = threadIdx.x; t < NBINS; t += 256)
    joint[t] = (float)gh[t] * (1.0f / 65536.0f);   // total==65536 exactly
  __syncthreads();

  if (threadIdx.x < NB) {
    const int i = threadIdx.x;
    float sx = 0.f, sy = 0.f;
    for (int j = 0; j < NB; ++j) {
      sx += joint[i * NB + j];   // x_hist[i]
      sy += joint[j * NB + i];   // y_hist[i]
    }
    xh[i] = sx; yh[i] = sy;
  }
  __syncthreads();

  float mi_part = 0.f;
  for (int t = threadIdx.x; t < NBINS; t += 256) {
    const int i = t / NB, j = t % NB;
    const float je = joint[t] + 1e-5f;
    const float pe = (xh[i] + 1e-5f) * (yh[j] + 1e-5f);
    mi_part += je * (logf(je) - logf(pe));
  }
  float h_part = 0.f;
  if (threadIdx.x < NB) {
    const float e = xh[threadIdx.x] + 1e-5f;
    h_part = -(e * logf(e));                        // hx term
  } else if (threadIdx.x >= 64 && threadIdx.x < 64 + NB) {
    const float e = yh[threadIdx.x - 64] + 1e-5f;
    h_part = -(e * logf(e));                        // hy term
  }

  for (int o = 32; o > 0; o >>= 1) {
    mi_part += __shfl_down(mi_part, o);
    h_part  += __shfl_down(h_part, o);
  }
  const int wid  = threadIdx.x >> 6;
  const int lane = threadIdx.x & 63;
  if (lane == 0) { red_mi[wid] = mi_part; red_h[wid] = h_part; }
  __syncthreads();

  if (threadIdx.x == 0) {
    const float mi = red_mi[0] + red_mi[1] + red_mi[2] + red_mi[3];
    const float se = red_h[0] + red_h[1] + red_h[2] + red_h[3];  // hx + hy
    float nmi = (se < 1e-10f) ? 0.0f : (2.0f * mi / se);
    nmi = fminf(fmaxf(nmi, -1.0f), 1.0f);
    __hip_atomic_store(&nmi_arr[b], nmi, __ATOMIC_RELEASE,
                       __HIP_MEMORY_SCOPE_AGENT);
    const uint32_t t = __hip_atomic_fetch_add(ctr, 1u, __ATOMIC_ACQ_REL,
                                              __HIP_MEMORY_SCOPE_AGENT);
    islast = (t == (uint32_t)(NBATCH - 1));
  }
  __syncthreads();

  if (islast && threadIdx.x < 64) {
    float v = __hip_atomic_load(&nmi_arr[threadIdx.x], __ATOMIC_ACQUIRE,
                                __HIP_MEMORY_SCOPE_AGENT);
    for (int o = 32; o > 0; o >>= 1) v += __shfl_down(v, o);
    if (threadIdx.x == 0) {
      float m = v * (1.0f / 64.0f);                  // mean (exact /2^6)
      m = fminf(fmaxf(m, -1.0f), 1.0f);
      out[0] = -m;
    }
  }
}

extern "C" void kernel_launch(void* const* d_in, const int* in_sizes, int n_in,
                              void* d_out, int out_size, void* d_ws, size_t ws_size,
                              hipStream_t stream) {
  const float* x = (const float*)d_in[0];
  const float* y = (const float*)d_in[1];
  float* out = (float*)d_out;

  // ws layout: ghist (64*576 u32 = 147456 B) | ctr (u32, @147456) |
  //            nmi (64 f32, @147520)
  uint32_t* ghist = (uint32_t*)d_ws;
  uint32_t* ctr   = (uint32_t*)((char*)d_ws + 147456);
  float*    nmi   = (float*)((char*)d_ws + 147520);

  // Host-side key derivation:
  // jax.random.split(jax.random.key(42)) under threefry_partitionable:
  //   nk_i = threefry2x32((0,42), count=(hi=0, lo=i)), both output words.
  uint32_t nk1a = 0u, nk1b = 0u; threefry2x32_(0u, 42u, nk1a, nk1b);
  uint32_t nk2a = 0u, nk2b = 1u; threefry2x32_(0u, 42u, nk2a, nk2b);

  hipMemsetAsync(d_ws, 0, 147520 + NBATCH * sizeof(float), stream);
  nmi_hist_kernel<<<NBATCH * HIST_BPB, HIST_THREADS, 0, stream>>>(
      x, y, ghist, nk1a, nk1b, nk2a, nk2b);
  nmi_reduce_kernel<<<NBATCH, 256, 0, stream>>>(ghist, nmi, ctr, out);
}